// Round 1
// baseline (1854.904 us; speedup 1.0000x reference)
//
#include <hip/hip_runtime.h>
#include <math.h>

#define N_NODES 50000
#define N_EDGES 800000
#define NFEAT   512
#define HID     96
#define NCLASS  64
#define NUM_LAYERS 8
#define ALPHA   0.1f

// ---------------- CSR build ----------------
__global__ void hist_kernel(const int* __restrict__ dst, int* __restrict__ deg) {
    int e = blockIdx.x * blockDim.x + threadIdx.x;
    if (e < N_EDGES) atomicAdd(&deg[dst[e]], 1);
}

__global__ void scan_kernel(const int* __restrict__ deg, int* __restrict__ row_start) {
    __shared__ int sdata[1024];
    __shared__ int s_carry;
    int tid = threadIdx.x;
    if (tid == 0) s_carry = 0;
    __syncthreads();
    for (int base = 0; base < N_NODES; base += 1024) {
        int i = base + tid;
        int v = (i < N_NODES) ? deg[i] : 0;
        sdata[tid] = v;
        __syncthreads();
        for (int off = 1; off < 1024; off <<= 1) {
            int t = (tid >= off) ? sdata[tid - off] : 0;
            __syncthreads();
            sdata[tid] += t;
            __syncthreads();
        }
        int carry = s_carry;
        if (i < N_NODES) row_start[i] = carry + sdata[tid] - v;
        __syncthreads();                    // everyone read s_carry
        if (tid == 1023) s_carry = carry + sdata[1023];
        __syncthreads();
    }
}

__global__ void fill_kernel(const int* __restrict__ src, const int* __restrict__ dst,
                            const int* __restrict__ row_start, int* __restrict__ cursor,
                            int* __restrict__ csr_src) {
    int e = blockIdx.x * blockDim.x + threadIdx.x;
    if (e < N_EDGES) {
        int d = dst[e];
        int pos = row_start[d] + atomicAdd(&cursor[d], 1);
        csr_src[pos] = src[e];
    }
}

// ---------------- input GEMM: h = relu(x @ W_in + b_in), also writes x0 ----------------
// 64 rows x 96 cols per block, 256 threads, K-chunks of 32.
__global__ __launch_bounds__(256) void gemm_in_kernel(
        const float* __restrict__ x, const float* __restrict__ W,
        const float* __restrict__ b, float* __restrict__ h, float* __restrict__ x0) {
    __shared__ float As[32][65];   // [k][row], padded
    __shared__ float Bs[32][97];   // [k][col], padded
    int tid  = threadIdx.x;
    int row0 = blockIdx.x * 64;
    int r0 = (tid >> 4) * 4;       // 0..60
    int c0 = (tid & 15) * 6;       // 0..90
    float acc[4][6];
#pragma unroll
    for (int i = 0; i < 4; i++)
#pragma unroll
        for (int j = 0; j < 6; j++) acc[i][j] = 0.f;

    for (int k0 = 0; k0 < NFEAT; k0 += 32) {
        // A tile: 64 rows x 32 k = 512 float4 slots
#pragma unroll
        for (int it = 0; it < 2; it++) {
            int s = tid + it * 256;
            int r = s >> 3, kq = s & 7;
            int gr = row0 + r; if (gr >= N_NODES) gr = N_NODES - 1;
            float4 v = *(const float4*)&x[(size_t)gr * NFEAT + k0 + kq * 4];
            As[kq*4+0][r] = v.x; As[kq*4+1][r] = v.y;
            As[kq*4+2][r] = v.z; As[kq*4+3][r] = v.w;
        }
        // B tile: 32 k x 96 cols = 768 float4 slots
#pragma unroll
        for (int it = 0; it < 3; it++) {
            int s = tid + it * 256;
            int kk = s / 24, cq = s % 24;
            float4 v = *(const float4*)&W[(size_t)(k0 + kk) * HID + cq * 4];
            Bs[kk][cq*4+0] = v.x; Bs[kk][cq*4+1] = v.y;
            Bs[kk][cq*4+2] = v.z; Bs[kk][cq*4+3] = v.w;
        }
        __syncthreads();
#pragma unroll 8
        for (int kk = 0; kk < 32; kk++) {
            float a[4], bb[6];
#pragma unroll
            for (int i = 0; i < 4; i++) a[i] = As[kk][r0 + i];
#pragma unroll
            for (int j = 0; j < 6; j++) bb[j] = Bs[kk][c0 + j];
#pragma unroll
            for (int i = 0; i < 4; i++)
#pragma unroll
                for (int j = 0; j < 6; j++) acc[i][j] += a[i] * bb[j];
        }
        __syncthreads();
    }
#pragma unroll
    for (int i = 0; i < 4; i++) {
        int gr = row0 + r0 + i;
        if (gr < N_NODES) {
#pragma unroll
            for (int j = 0; j < 6; j++) {
                float v = acc[i][j] + b[c0 + j];
                v = v > 0.f ? v : 0.f;
                h[(size_t)gr * HID + c0 + j]  = v;
                x0[(size_t)gr * HID + c0 + j] = v;
            }
        }
    }
}

// ---------------- aggregation + residual mix: hc = 0.9*agg + 0.1*x0 ----------------
// 96 threads per node (one per feature), 4 nodes per block.
__global__ __launch_bounds__(384) void agg_kernel(
        const float* __restrict__ h, const float* __restrict__ x0,
        const int* __restrict__ row_start, const int* __restrict__ deg,
        const int* __restrict__ csr_src, float* __restrict__ hc) {
    int node = blockIdx.x * 4 + threadIdx.y;
    int f = threadIdx.x;
    int s = row_start[node], d = deg[node];
    float acc = 0.f;
    for (int i = 0; i < d; i++) {
        int src = csr_src[s + i];
        acc += h[(size_t)src * HID + f];
    }
    hc[(size_t)node * HID + f] =
        (1.0f - ALPHA) * acc + ALPHA * x0[(size_t)node * HID + f];
}

// ---------------- conv layer: h = relu((1-beta)*hc + beta*(hc @ W_l)) ----------------
// block (24,16): 16 rows, thread tx owns 4 consecutive cols (float4), W staged in LDS.
__global__ __launch_bounds__(384) void conv_kernel(
        const float* __restrict__ hc, const float* __restrict__ W,
        float beta, float* __restrict__ h_out) {
    __shared__ float4 Ws[96][25];   // [k][col/4], padded
    __shared__ float  As[16][97];   // [row][k], padded
    int tx = threadIdx.x;           // 0..23
    int ty = threadIdx.y;           // 0..15
    int tid = ty * 24 + tx;
    int row0 = blockIdx.x * 16;
    const float4* W4 = (const float4*)W;
    for (int s = tid; s < 96 * 24; s += 384) Ws[s / 24][s % 24] = W4[s];
    for (int s = tid; s < 16 * 96; s += 384)
        As[s / 96][s % 96] = hc[(size_t)row0 * HID + s];
    __syncthreads();
    float4 acc = {0.f, 0.f, 0.f, 0.f};
#pragma unroll 8
    for (int k = 0; k < 96; k++) {
        float a = As[ty][k];
        float4 w = Ws[k][tx];
        acc.x += a * w.x; acc.y += a * w.y; acc.z += a * w.z; acc.w += a * w.w;
    }
    int c0 = tx * 4;
    float ob = 1.0f - beta;
    float* outp = &h_out[(size_t)(row0 + ty) * HID + c0];
    float h0 = ob * As[ty][c0 + 0] + beta * acc.x;
    float h1 = ob * As[ty][c0 + 1] + beta * acc.y;
    float h2 = ob * As[ty][c0 + 2] + beta * acc.z;
    float h3 = ob * As[ty][c0 + 3] + beta * acc.w;
    outp[0] = h0 > 0.f ? h0 : 0.f;
    outp[1] = h1 > 0.f ? h1 : 0.f;
    outp[2] = h2 > 0.f ? h2 : 0.f;
    outp[3] = h3 > 0.f ? h3 : 0.f;
}

// ---------------- output GEMM + log_softmax: one wave per row, lane = class ----------------
__global__ __launch_bounds__(256) void out_kernel(
        const float* __restrict__ h, const float* __restrict__ W,
        const float* __restrict__ b, float* __restrict__ out) {
    int wave = (blockIdx.x * 256 + threadIdx.x) >> 6;
    int lane = threadIdx.x & 63;
    if (wave >= N_NODES) return;
    const float* hrow = &h[(size_t)wave * HID];
    float acc = b[lane];
#pragma unroll 8
    for (int k = 0; k < HID; k++) acc += hrow[k] * W[k * NCLASS + lane];
    float m = acc;
#pragma unroll
    for (int off = 32; off >= 1; off >>= 1) {
        float o = __shfl_xor(m, off);
        m = m > o ? m : o;
    }
    float e = __expf(acc - m);
    float ssum = e;
#pragma unroll
    for (int off = 32; off >= 1; off >>= 1) ssum += __shfl_xor(ssum, off);
    out[(size_t)wave * NCLASS + lane] = acc - m - __logf(ssum);
}

extern "C" void kernel_launch(void* const* d_in, const int* in_sizes, int n_in,
                              void* d_out, int out_size, void* d_ws, size_t ws_size,
                              hipStream_t stream) {
    const float* x      = (const float*)d_in[0];
    const int*   ei     = (const int*)d_in[1];
    const int*   srcp   = ei;
    const int*   dstp   = ei + N_EDGES;
    const float* W_in   = (const float*)d_in[2];
    const float* b_in   = (const float*)d_in[3];
    const float* conv_W = (const float*)d_in[4];
    const float* W_out  = (const float*)d_in[5];
    const float* b_out  = (const float*)d_in[6];
    float* out = (float*)d_out;

    float* h  = (float*)d_ws;
    float* x0 = h  + (size_t)N_NODES * HID;
    float* hc = x0 + (size_t)N_NODES * HID;
    int* deg       = (int*)(hc + (size_t)N_NODES * HID);
    int* row_start = deg + N_NODES;
    int* cursor    = row_start + N_NODES + 2;
    int* csr_src   = cursor + N_NODES;

    hipMemsetAsync(deg,    0, N_NODES * sizeof(int), stream);
    hipMemsetAsync(cursor, 0, N_NODES * sizeof(int), stream);
    hist_kernel<<<(N_EDGES + 255) / 256, 256, 0, stream>>>(dstp, deg);
    scan_kernel<<<1, 1024, 0, stream>>>(deg, row_start);
    fill_kernel<<<(N_EDGES + 255) / 256, 256, 0, stream>>>(srcp, dstp, row_start, cursor, csr_src);

    gemm_in_kernel<<<(N_NODES + 63) / 64, 256, 0, stream>>>(x, W_in, b_in, h, x0);

    for (int l = 0; l < NUM_LAYERS; l++) {
        float beta = logf(0.5f / (float)(l + 1) + 1.0f);
        agg_kernel<<<N_NODES / 4, dim3(96, 4), 0, stream>>>(h, x0, row_start, deg, csr_src, hc);
        conv_kernel<<<N_NODES / 16, dim3(24, 16), 0, stream>>>(
            hc, conv_W + (size_t)l * HID * HID, beta, h);
    }

    out_kernel<<<(N_NODES + 3) / 4, 256, 0, stream>>>(h, W_out, b_out, out);
}

// Round 3
// 1008.555 us; speedup vs baseline: 1.8392x; 1.8392x over previous
//
#include <hip/hip_runtime.h>
#include <math.h>

#define N_NODES 50000
#define N_EDGES 800000
#define NFEAT   512
#define HID     96
#define NCLASS  64
#define NUM_LAYERS 8
#define ALPHA   0.1f

// ---------------- CSR build (rows padded to multiple of 4, dummy = N_NODES) ----------------
__global__ void hist_kernel(const int* __restrict__ dst, int* __restrict__ deg) {
    int e = blockIdx.x * blockDim.x + threadIdx.x;
    if (e < N_EDGES) atomicAdd(&deg[dst[e]], 1);
}

__global__ void scan_kernel(const int* __restrict__ deg, int* __restrict__ row_start) {
    __shared__ int sdata[1024];
    __shared__ int s_carry;
    int tid = threadIdx.x;
    if (tid == 0) s_carry = 0;
    __syncthreads();
    for (int base = 0; base < N_NODES; base += 1024) {
        int i = base + tid;
        int v = (i < N_NODES) ? ((deg[i] + 3) & ~3) : 0;   // padded degree
        sdata[tid] = v;
        __syncthreads();
        for (int off = 1; off < 1024; off <<= 1) {
            int t = (tid >= off) ? sdata[tid - off] : 0;
            __syncthreads();
            sdata[tid] += t;
            __syncthreads();
        }
        int carry = s_carry;
        if (i < N_NODES) row_start[i] = carry + sdata[tid] - v;
        __syncthreads();
        if (tid == 1023) s_carry = carry + sdata[1023];
        __syncthreads();
    }
}

__global__ void fill_kernel(const int* __restrict__ src, const int* __restrict__ dst,
                            const int* __restrict__ row_start, int* __restrict__ cursor,
                            int* __restrict__ csr_src) {
    int e = blockIdx.x * blockDim.x + threadIdx.x;
    if (e < N_EDGES) {
        int d = dst[e];
        int pos = row_start[d] + atomicAdd(&cursor[d], 1);
        csr_src[pos] = src[e];
    }
}

__global__ void pad_kernel(const int* __restrict__ deg, const int* __restrict__ row_start,
                           int* __restrict__ csr_src) {
    int n = blockIdx.x * blockDim.x + threadIdx.x;
    if (n < N_NODES) {
        int d = deg[n], pd = (d + 3) & ~3, rs = row_start[n];
        for (int p = d; p < pd; p++) csr_src[rs + p] = N_NODES;  // dummy zero row
    }
}

__global__ void zero_dummy_kernel(float* __restrict__ ha, float* __restrict__ hb) {
    int t = threadIdx.x;
    if (t < HID) {
        ha[(size_t)N_NODES * HID + t] = 0.f;
        hb[(size_t)N_NODES * HID + t] = 0.f;
    }
}

// ---------------- input GEMM: h = relu(x @ W_in + b_in), also writes x0 ----------------
__global__ __launch_bounds__(256) void gemm_in_kernel(
        const float* __restrict__ x, const float* __restrict__ W,
        const float* __restrict__ b, float* __restrict__ h, float* __restrict__ x0) {
    __shared__ float As[32][65];   // [k][row], padded
    __shared__ float Bs[32][97];   // [k][col], padded
    int tid  = threadIdx.x;
    int row0 = blockIdx.x * 64;
    int r0 = (tid >> 4) * 4;       // 0..60
    int c0 = (tid & 15) * 6;       // 0..90
    float acc[4][6];
#pragma unroll
    for (int i = 0; i < 4; i++)
#pragma unroll
        for (int j = 0; j < 6; j++) acc[i][j] = 0.f;

    for (int k0 = 0; k0 < NFEAT; k0 += 32) {
#pragma unroll
        for (int it = 0; it < 2; it++) {
            int s = tid + it * 256;
            int r = s >> 3, kq = s & 7;
            int gr = row0 + r; if (gr >= N_NODES) gr = N_NODES - 1;
            float4 v = *(const float4*)&x[(size_t)gr * NFEAT + k0 + kq * 4];
            As[kq*4+0][r] = v.x; As[kq*4+1][r] = v.y;
            As[kq*4+2][r] = v.z; As[kq*4+3][r] = v.w;
        }
#pragma unroll
        for (int it = 0; it < 3; it++) {
            int s = tid + it * 256;
            int kk = s / 24, cq = s % 24;
            float4 v = *(const float4*)&W[(size_t)(k0 + kk) * HID + cq * 4];
            Bs[kk][cq*4+0] = v.x; Bs[kk][cq*4+1] = v.y;
            Bs[kk][cq*4+2] = v.z; Bs[kk][cq*4+3] = v.w;
        }
        __syncthreads();
#pragma unroll 8
        for (int kk = 0; kk < 32; kk++) {
            float a[4], bb[6];
#pragma unroll
            for (int i = 0; i < 4; i++) a[i] = As[kk][r0 + i];
#pragma unroll
            for (int j = 0; j < 6; j++) bb[j] = Bs[kk][c0 + j];
#pragma unroll
            for (int i = 0; i < 4; i++)
#pragma unroll
                for (int j = 0; j < 6; j++) acc[i][j] += a[i] * bb[j];
        }
        __syncthreads();
    }
#pragma unroll
    for (int i = 0; i < 4; i++) {
        int gr = row0 + r0 + i;
        if (gr < N_NODES) {
#pragma unroll
            for (int j = 0; j < 6; j++) {
                float v = acc[i][j] + b[c0 + j];
                v = v > 0.f ? v : 0.f;
                h[(size_t)gr * HID + c0 + j]  = v;
                x0[(size_t)gr * HID + c0 + j] = v;
            }
        }
    }
}

// ---------------- fused layer: agg (CSR gather) + residual mix + 96x96 GEMM + relu ----------
// block (24,16): ty = node (16/block), tx = float4 feature chunk (24 = 96/4).
// h_in != h_out (ping-pong) — in-place is a cross-block race.
__global__ __launch_bounds__(384) void layer_kernel(
        const float* __restrict__ h_in, const float* __restrict__ x0,
        const int* __restrict__ row_start, const int* __restrict__ deg,
        const int* __restrict__ csr_src, const float* __restrict__ W,
        float beta, float* __restrict__ h_out) {
    __shared__ float4 Ws[96][25];   // [k][col/4], padded
    __shared__ float  As[16][100];  // [row][k] = hc, padded
    int tx = threadIdx.x;           // 0..23
    int ty = threadIdx.y;           // 0..15
    int tid = ty * 24 + tx;
    int row0 = blockIdx.x * 16;

    // stage W into LDS (in flight during the gather below)
    const float4* W4 = (const float4*)W;
    for (int s = tid; s < 96 * 24; s += 384) Ws[s / 24][s % 24] = W4[s];

    // aggregation: 4 edges per iteration, int4 index load + 4 independent float4 gathers
    int node = row0 + ty;
    int s = row_start[node];
    int d = deg[node];
    int nq = (d + 3) >> 2;
    const float4* h4 = (const float4*)h_in;
    const int4* c4 = (const int4*)(csr_src + s);
    float4 acc0 = {0.f,0.f,0.f,0.f}, acc1 = {0.f,0.f,0.f,0.f};
    for (int i = 0; i < nq; i++) {
        int4 idx = c4[i];
        float4 a0 = h4[(size_t)idx.x * 24 + tx];
        float4 a1 = h4[(size_t)idx.y * 24 + tx];
        float4 a2 = h4[(size_t)idx.z * 24 + tx];
        float4 a3 = h4[(size_t)idx.w * 24 + tx];
        acc0.x += a0.x + a2.x; acc0.y += a0.y + a2.y;
        acc0.z += a0.z + a2.z; acc0.w += a0.w + a2.w;
        acc1.x += a1.x + a3.x; acc1.y += a1.y + a3.y;
        acc1.z += a1.z + a3.z; acc1.w += a1.w + a3.w;
    }
    float4 r = ((const float4*)x0)[(size_t)node * 24 + tx];
    float4 hc;
    hc.x = (1.f - ALPHA) * (acc0.x + acc1.x) + ALPHA * r.x;
    hc.y = (1.f - ALPHA) * (acc0.y + acc1.y) + ALPHA * r.y;
    hc.z = (1.f - ALPHA) * (acc0.z + acc1.z) + ALPHA * r.z;
    hc.w = (1.f - ALPHA) * (acc0.w + acc1.w) + ALPHA * r.w;
    *(float4*)&As[ty][tx * 4] = hc;
    __syncthreads();

    // GEMM: h = relu((1-beta)*hc + beta*(hc @ W))
    float4 acc = {0.f,0.f,0.f,0.f};
#pragma unroll 8
    for (int k = 0; k < 96; k++) {
        float a = As[ty][k];
        float4 w = Ws[k][tx];
        acc.x += a * w.x; acc.y += a * w.y; acc.z += a * w.z; acc.w += a * w.w;
    }
    int c0 = tx * 4;
    float ob = 1.0f - beta;
    float* outp = &h_out[(size_t)(row0 + ty) * HID + c0];
    float h0 = ob * As[ty][c0 + 0] + beta * acc.x;
    float h1 = ob * As[ty][c0 + 1] + beta * acc.y;
    float h2 = ob * As[ty][c0 + 2] + beta * acc.z;
    float h3 = ob * As[ty][c0 + 3] + beta * acc.w;
    outp[0] = h0 > 0.f ? h0 : 0.f;
    outp[1] = h1 > 0.f ? h1 : 0.f;
    outp[2] = h2 > 0.f ? h2 : 0.f;
    outp[3] = h3 > 0.f ? h3 : 0.f;
}

// ---------------- output GEMM + log_softmax: one wave per row, lane = class ----------------
__global__ __launch_bounds__(256) void out_kernel(
        const float* __restrict__ h, const float* __restrict__ W,
        const float* __restrict__ b, float* __restrict__ out) {
    int wave = (blockIdx.x * 256 + threadIdx.x) >> 6;
    int lane = threadIdx.x & 63;
    if (wave >= N_NODES) return;
    const float* hrow = &h[(size_t)wave * HID];
    float acc = b[lane];
#pragma unroll 8
    for (int k = 0; k < HID; k++) acc += hrow[k] * W[k * NCLASS + lane];
    float m = acc;
#pragma unroll
    for (int off = 32; off >= 1; off >>= 1) {
        float o = __shfl_xor(m, off);
        m = m > o ? m : o;
    }
    float e = __expf(acc - m);
    float ssum = e;
#pragma unroll
    for (int off = 32; off >= 1; off >>= 1) ssum += __shfl_xor(ssum, off);
    out[(size_t)wave * NCLASS + lane] = acc - m - __logf(ssum);
}

extern "C" void kernel_launch(void* const* d_in, const int* in_sizes, int n_in,
                              void* d_out, int out_size, void* d_ws, size_t ws_size,
                              hipStream_t stream) {
    const float* x      = (const float*)d_in[0];
    const int*   ei     = (const int*)d_in[1];
    const int*   srcp   = ei;
    const int*   dstp   = ei + N_EDGES;
    const float* W_in   = (const float*)d_in[2];
    const float* b_in   = (const float*)d_in[3];
    const float* conv_W = (const float*)d_in[4];
    const float* W_out  = (const float*)d_in[5];
    const float* b_out  = (const float*)d_in[6];
    float* out = (float*)d_out;

    float* h_a = (float*)d_ws;                               // (N_NODES+1) x HID
    float* h_b = h_a + (size_t)(N_NODES + 1) * HID;          // (N_NODES+1) x HID
    float* x0  = h_b + (size_t)(N_NODES + 1) * HID;          // N_NODES x HID
    int* deg       = (int*)(x0 + (size_t)N_NODES * HID);
    int* row_start = deg + N_NODES;
    int* cursor    = row_start + N_NODES;
    int* csr_src   = cursor + N_NODES;                       // <= N_EDGES + 3*N_NODES ints

    hipMemsetAsync(deg,    0, N_NODES * sizeof(int), stream);
    hipMemsetAsync(cursor, 0, N_NODES * sizeof(int), stream);
    hist_kernel<<<(N_EDGES + 255) / 256, 256, 0, stream>>>(dstp, deg);
    scan_kernel<<<1, 1024, 0, stream>>>(deg, row_start);
    fill_kernel<<<(N_EDGES + 255) / 256, 256, 0, stream>>>(srcp, dstp, row_start, cursor, csr_src);
    pad_kernel<<<(N_NODES + 255) / 256, 256, 0, stream>>>(deg, row_start, csr_src);

    gemm_in_kernel<<<(N_NODES + 63) / 64, 256, 0, stream>>>(x, W_in, b_in, h_a, x0);
    zero_dummy_kernel<<<1, 128, 0, stream>>>(h_a, h_b);

    float* cur = h_a;
    float* nxt = h_b;
    for (int l = 0; l < NUM_LAYERS; l++) {
        float beta = logf(0.5f / (float)(l + 1) + 1.0f);
        layer_kernel<<<N_NODES / 16, dim3(24, 16), 0, stream>>>(
            cur, x0, row_start, deg, csr_src, conv_W + (size_t)l * HID * HID, beta, nxt);
        float* t = cur; cur = nxt; nxt = t;
    }

    out_kernel<<<(N_NODES + 3) / 4, 256, 0, stream>>>(cur, W_out, b_out, out);
}

// Round 4
// 892.986 us; speedup vs baseline: 2.0772x; 1.1294x over previous
//
#include <hip/hip_runtime.h>
#include <math.h>

#define N_NODES 50000
#define N_EDGES 800000
#define NFEAT   512
#define HID     96
#define NCLASS  64
#define NUM_LAYERS 8
#define ALPHA   0.1f
#define NSB     49          // scan blocks: ceil(50000/1024)

typedef __attribute__((ext_vector_type(8))) short short8;
typedef __attribute__((ext_vector_type(4))) float f32x4;

__device__ __forceinline__ unsigned short f2bf(float f) {
    unsigned int u = __float_as_uint(f);
    unsigned int r = u + 0x7FFF + ((u >> 16) & 1);   // round-to-nearest-even
    return (unsigned short)(r >> 16);
}

// ---------------- CSR build (rows padded to multiple of 4, dummy = N_NODES) ----------------
__global__ void hist_kernel(const int* __restrict__ dst, int* __restrict__ deg) {
    int e = blockIdx.x * blockDim.x + threadIdx.x;
    if (e < N_EDGES) atomicAdd(&deg[dst[e]], 1);
}

__global__ void scan1_kernel(const int* __restrict__ deg, int* __restrict__ row_start,
                             int* __restrict__ blk_sum) {
    __shared__ int sd[1024];
    int t = threadIdx.x;
    int i = blockIdx.x * 1024 + t;
    int v = (i < N_NODES) ? ((deg[i] + 3) & ~3) : 0;   // padded degree
    sd[t] = v;
    __syncthreads();
    for (int off = 1; off < 1024; off <<= 1) {
        int tv = (t >= off) ? sd[t - off] : 0;
        __syncthreads();
        sd[t] += tv;
        __syncthreads();
    }
    if (i < N_NODES) row_start[i] = sd[t] - v;          // exclusive, block-local
    if (t == 1023) blk_sum[blockIdx.x] = sd[1023];
}

__global__ void scan2_kernel(const int* __restrict__ blk_sum, int* __restrict__ blk_off) {
    if (threadIdx.x == 0) {
        int acc = 0;
        for (int b = 0; b < NSB; b++) { blk_off[b] = acc; acc += blk_sum[b]; }
    }
}

__global__ void scan3_kernel(int* __restrict__ row_start, const int* __restrict__ blk_off) {
    int i = blockIdx.x * 1024 + threadIdx.x;
    if (i < N_NODES) row_start[i] += blk_off[blockIdx.x];
}

__global__ void fill_kernel(const int* __restrict__ src, const int* __restrict__ dst,
                            const int* __restrict__ row_start, int* __restrict__ cursor,
                            int* __restrict__ csr_src) {
    int e = blockIdx.x * blockDim.x + threadIdx.x;
    if (e < N_EDGES) {
        int d = dst[e];
        int pos = row_start[d] + atomicAdd(&cursor[d], 1);
        csr_src[pos] = src[e];
    }
}

__global__ void pad_kernel(const int* __restrict__ deg, const int* __restrict__ row_start,
                           int* __restrict__ csr_src) {
    int n = blockIdx.x * blockDim.x + threadIdx.x;
    if (n < N_NODES) {
        int d = deg[n], pd = (d + 3) & ~3, rs = row_start[n];
        for (int p = d; p < pd; p++) csr_src[rs + p] = N_NODES;  // dummy zero row
    }
}

__global__ void zero_dummy_kernel(float* __restrict__ ha, float* __restrict__ hb) {
    int t = threadIdx.x;
    if (t < HID) {
        ha[(size_t)N_NODES * HID + t] = 0.f;
        hb[(size_t)N_NODES * HID + t] = 0.f;
    }
}

// ---------------- W_in convert+transpose: Wt[n][k] = bf16(W[k][n]) ----------------
__global__ void convert_w_kernel(const float* __restrict__ W, short* __restrict__ Wt) {
    int n = blockIdx.x;    // 0..95
    int k = threadIdx.x;   // 0..511
    Wt[(size_t)n * NFEAT + k] = (short)f2bf(W[(size_t)k * HID + n]);
}

// ---------------- input GEMM via MFMA bf16: h = relu(x @ W_in + b_in), also x0 ----------
// 64 rows x 96 cols per block; 4 waves, wave w = rows 16w..16w+15, 6 n-tiles each.
__global__ __launch_bounds__(256) void gemm_in_kernel(
        const float* __restrict__ x, const short* __restrict__ Wt,
        const float* __restrict__ b, float* __restrict__ h, float* __restrict__ x0) {
    __shared__ short A_lds[64 * 40];   // row stride 40 shorts = 80 B (16B-aligned, conflict-spread)
    int tid  = threadIdx.x;
    int wave = tid >> 6, lane = tid & 63;
    int quad = lane >> 4, l16 = lane & 15;
    int row0 = blockIdx.x * 64;
    int m0   = wave * 16;

    f32x4 acc[6];
#pragma unroll
    for (int n = 0; n < 6; n++) acc[n] = (f32x4){0.f, 0.f, 0.f, 0.f};

    for (int k0 = 0; k0 < NFEAT; k0 += 32) {
        // stage A tile: 64 rows x 32 k, fp32 -> bf16
#pragma unroll
        for (int it = 0; it < 2; it++) {
            int s = tid + it * 256;          // 0..511
            int r = s >> 3, kq = s & 7;      // 8 float4 per row
            int gr = row0 + r; if (gr >= N_NODES) gr = N_NODES - 1;
            float4 v = *(const float4*)&x[(size_t)gr * NFEAT + k0 + kq * 4];
            uint2 pk;
            pk.x = (unsigned)f2bf(v.x) | ((unsigned)f2bf(v.y) << 16);
            pk.y = (unsigned)f2bf(v.z) | ((unsigned)f2bf(v.w) << 16);
            *(uint2*)&A_lds[r * 40 + kq * 4] = pk;
        }
        __syncthreads();
        // A fragment: lane holds A[m=l16][k = quad*8 + j]
        short8 afrag = *(const short8*)&A_lds[(m0 + l16) * 40 + quad * 8];
#pragma unroll
        for (int n = 0; n < 6; n++) {
            // B fragment: lane holds B[k=quad*8+j][col = n*16+l16] = Wt[col][k0+quad*8+j]
            short8 bfrag = *(const short8*)&Wt[(size_t)(n * 16 + l16) * NFEAT + k0 + quad * 8];
            acc[n] = __builtin_amdgcn_mfma_f32_16x16x32_bf16(afrag, bfrag, acc[n], 0, 0, 0);
        }
        __syncthreads();
    }
    // epilogue: C/D layout col=lane&15, row=quad*4+reg
#pragma unroll
    for (int n = 0; n < 6; n++) {
        int col = n * 16 + l16;
        float bias = b[col];
#pragma unroll
        for (int r = 0; r < 4; r++) {
            int grow = row0 + m0 + quad * 4 + r;
            if (grow < N_NODES) {
                float v = acc[n][r] + bias;
                v = v > 0.f ? v : 0.f;
                h[(size_t)grow * HID + col]  = v;
                x0[(size_t)grow * HID + col] = v;
            }
        }
    }
}

// ---------------- fused layer: agg (CSR gather) + residual mix + 96x96 GEMM + relu ----------
// block (24,16): ty = node (16/block), tx = float4 feature chunk (24 = 96/4).
// h_in != h_out (ping-pong) — in-place is a cross-block race.
__global__ __launch_bounds__(384) void layer_kernel(
        const float* __restrict__ h_in, const float* __restrict__ x0,
        const int* __restrict__ row_start, const int* __restrict__ deg,
        const int* __restrict__ csr_src, const float* __restrict__ W,
        float beta, float* __restrict__ h_out) {
    __shared__ float4 Ws[96][25];   // [k][col/4], padded
    __shared__ float  As[16][100];  // [row][k] = hc, padded
    int tx = threadIdx.x;           // 0..23
    int ty = threadIdx.y;           // 0..15
    int tid = ty * 24 + tx;
    int row0 = blockIdx.x * 16;

    const float4* W4 = (const float4*)W;
    for (int s = tid; s < 96 * 24; s += 384) Ws[s / 24][s % 24] = W4[s];

    int node = row0 + ty;
    int s = row_start[node];
    int d = deg[node];
    int nq = (d + 3) >> 2;
    const float4* h4 = (const float4*)h_in;
    const int4* c4 = (const int4*)(csr_src + s);
    float4 acc0 = {0.f,0.f,0.f,0.f}, acc1 = {0.f,0.f,0.f,0.f};
    for (int i = 0; i < nq; i++) {
        int4 idx = c4[i];
        float4 a0 = h4[(size_t)idx.x * 24 + tx];
        float4 a1 = h4[(size_t)idx.y * 24 + tx];
        float4 a2 = h4[(size_t)idx.z * 24 + tx];
        float4 a3 = h4[(size_t)idx.w * 24 + tx];
        acc0.x += a0.x + a2.x; acc0.y += a0.y + a2.y;
        acc0.z += a0.z + a2.z; acc0.w += a0.w + a2.w;
        acc1.x += a1.x + a3.x; acc1.y += a1.y + a3.y;
        acc1.z += a1.z + a3.z; acc1.w += a1.w + a3.w;
    }
    float4 r = ((const float4*)x0)[(size_t)node * 24 + tx];
    float4 hc;
    hc.x = (1.f - ALPHA) * (acc0.x + acc1.x) + ALPHA * r.x;
    hc.y = (1.f - ALPHA) * (acc0.y + acc1.y) + ALPHA * r.y;
    hc.z = (1.f - ALPHA) * (acc0.z + acc1.z) + ALPHA * r.z;
    hc.w = (1.f - ALPHA) * (acc0.w + acc1.w) + ALPHA * r.w;
    *(float4*)&As[ty][tx * 4] = hc;
    __syncthreads();

    float4 acc = {0.f,0.f,0.f,0.f};
#pragma unroll 8
    for (int k = 0; k < 96; k++) {
        float a = As[ty][k];
        float4 w = Ws[k][tx];
        acc.x += a * w.x; acc.y += a * w.y; acc.z += a * w.z; acc.w += a * w.w;
    }
    int c0 = tx * 4;
    float ob = 1.0f - beta;
    float* outp = &h_out[(size_t)(row0 + ty) * HID + c0];
    float h0 = ob * As[ty][c0 + 0] + beta * acc.x;
    float h1 = ob * As[ty][c0 + 1] + beta * acc.y;
    float h2 = ob * As[ty][c0 + 2] + beta * acc.z;
    float h3 = ob * As[ty][c0 + 3] + beta * acc.w;
    outp[0] = h0 > 0.f ? h0 : 0.f;
    outp[1] = h1 > 0.f ? h1 : 0.f;
    outp[2] = h2 > 0.f ? h2 : 0.f;
    outp[3] = h3 > 0.f ? h3 : 0.f;
}

// ---------------- output GEMM + log_softmax: one wave per row, lane = class ----------------
__global__ __launch_bounds__(256) void out_kernel(
        const float* __restrict__ h, const float* __restrict__ W,
        const float* __restrict__ b, float* __restrict__ out) {
    int wave = (blockIdx.x * 256 + threadIdx.x) >> 6;
    int lane = threadIdx.x & 63;
    if (wave >= N_NODES) return;
    const float* hrow = &h[(size_t)wave * HID];
    float acc = b[lane];
#pragma unroll 8
    for (int k = 0; k < HID; k++) acc += hrow[k] * W[k * NCLASS + lane];
    float m = acc;
#pragma unroll
    for (int off = 32; off >= 1; off >>= 1) {
        float o = __shfl_xor(m, off);
        m = m > o ? m : o;
    }
    float e = __expf(acc - m);
    float ssum = e;
#pragma unroll
    for (int off = 32; off >= 1; off >>= 1) ssum += __shfl_xor(ssum, off);
    out[(size_t)wave * NCLASS + lane] = acc - m - __logf(ssum);
}

extern "C" void kernel_launch(void* const* d_in, const int* in_sizes, int n_in,
                              void* d_out, int out_size, void* d_ws, size_t ws_size,
                              hipStream_t stream) {
    const float* x      = (const float*)d_in[0];
    const int*   ei     = (const int*)d_in[1];
    const int*   srcp   = ei;
    const int*   dstp   = ei + N_EDGES;
    const float* W_in   = (const float*)d_in[2];
    const float* b_in   = (const float*)d_in[3];
    const float* conv_W = (const float*)d_in[4];
    const float* W_out  = (const float*)d_in[5];
    const float* b_out  = (const float*)d_in[6];
    float* out = (float*)d_out;

    float* h_a = (float*)d_ws;                               // (N_NODES+1) x HID
    float* h_b = h_a + (size_t)(N_NODES + 1) * HID;          // (N_NODES+1) x HID
    float* x0  = h_b + (size_t)(N_NODES + 1) * HID;          // N_NODES x HID
    int* deg       = (int*)(x0 + (size_t)N_NODES * HID);
    int* row_start = deg + N_NODES;
    int* cursor    = row_start + N_NODES;
    int* blk_sum   = cursor + N_NODES;
    int* blk_off   = blk_sum + 64;
    int* csr_src   = blk_off + 64;                           // <= N_EDGES + 3*N_NODES ints
    short* Wt      = (short*)(csr_src + N_EDGES + 3 * N_NODES);  // 96*512 bf16

    hipMemsetAsync(deg,    0, N_NODES * sizeof(int), stream);
    hipMemsetAsync(cursor, 0, N_NODES * sizeof(int), stream);
    hist_kernel<<<(N_EDGES + 255) / 256, 256, 0, stream>>>(dstp, deg);
    scan1_kernel<<<NSB, 1024, 0, stream>>>(deg, row_start, blk_sum);
    scan2_kernel<<<1, 64, 0, stream>>>(blk_sum, blk_off);
    scan3_kernel<<<NSB, 1024, 0, stream>>>(row_start, blk_off);
    fill_kernel<<<(N_EDGES + 255) / 256, 256, 0, stream>>>(srcp, dstp, row_start, cursor, csr_src);
    pad_kernel<<<(N_NODES + 255) / 256, 256, 0, stream>>>(deg, row_start, csr_src);

    convert_w_kernel<<<HID, NFEAT, 0, stream>>>(W_in, Wt);
    gemm_in_kernel<<<(N_NODES + 63) / 64, 256, 0, stream>>>(x, Wt, b_in, h_a, x0);
    zero_dummy_kernel<<<1, 128, 0, stream>>>(h_a, h_b);

    float* cur = h_a;
    float* nxt = h_b;
    for (int l = 0; l < NUM_LAYERS; l++) {
        float beta = logf(0.5f / (float)(l + 1) + 1.0f);
        layer_kernel<<<N_NODES / 16, dim3(24, 16), 0, stream>>>(
            cur, x0, row_start, deg, csr_src, conv_W + (size_t)l * HID * HID, beta, nxt);
        float* t = cur; cur = nxt; nxt = t;
    }

    out_kernel<<<(N_NODES + 3) / 4, 256, 0, stream>>>(cur, W_out, b_out, out);
}

// Round 5
// 694.967 us; speedup vs baseline: 2.6691x; 1.2849x over previous
//
#include <hip/hip_runtime.h>
#include <math.h>

#define N_NODES 50000
#define N_EDGES 800000
#define NFEAT   512
#define HID     96
#define NCLASS  64
#define NUM_LAYERS 8
#define ALPHA   0.1f
#define NSB     49          // scan blocks: ceil(50000/1024)

typedef __attribute__((ext_vector_type(8))) short short8;
typedef __attribute__((ext_vector_type(4))) float f32x4;

__device__ __forceinline__ unsigned short f2bf(float f) {
    unsigned int u = __float_as_uint(f);
    unsigned int r = u + 0x7FFF + ((u >> 16) & 1);   // round-to-nearest-even
    return (unsigned short)(r >> 16);
}
__device__ __forceinline__ float bflo(unsigned int u) { return __uint_as_float(u << 16); }
__device__ __forceinline__ float bfhi(unsigned int u) { return __uint_as_float(u & 0xFFFF0000u); }

// ---------------- CSR build (rows padded to multiple of 4, dummy = N_NODES) ----------------
__global__ void hist_kernel(const int* __restrict__ dst, int* __restrict__ deg) {
    int e = blockIdx.x * blockDim.x + threadIdx.x;
    if (e < N_EDGES) atomicAdd(&deg[dst[e]], 1);
}

__global__ void scan1_kernel(const int* __restrict__ deg, int* __restrict__ row_start,
                             int* __restrict__ blk_sum) {
    __shared__ int sd[1024];
    int t = threadIdx.x;
    int i = blockIdx.x * 1024 + t;
    int v = (i < N_NODES) ? ((deg[i] + 3) & ~3) : 0;   // padded degree
    sd[t] = v;
    __syncthreads();
    for (int off = 1; off < 1024; off <<= 1) {
        int tv = (t >= off) ? sd[t - off] : 0;
        __syncthreads();
        sd[t] += tv;
        __syncthreads();
    }
    if (i < N_NODES) row_start[i] = sd[t] - v;          // exclusive, block-local
    if (t == 1023) blk_sum[blockIdx.x] = sd[1023];
}

__global__ void scan2_kernel(const int* __restrict__ blk_sum, int* __restrict__ blk_off) {
    if (threadIdx.x == 0) {
        int acc = 0;
        for (int b = 0; b < NSB; b++) { blk_off[b] = acc; acc += blk_sum[b]; }
    }
}

__global__ void scan3_kernel(int* __restrict__ row_start, const int* __restrict__ blk_off) {
    int i = blockIdx.x * 1024 + threadIdx.x;
    if (i < N_NODES) row_start[i] += blk_off[blockIdx.x];
}

__global__ void fill_kernel(const int* __restrict__ src, const int* __restrict__ dst,
                            const int* __restrict__ row_start, int* __restrict__ cursor,
                            int* __restrict__ csr_src) {
    int e = blockIdx.x * blockDim.x + threadIdx.x;
    if (e < N_EDGES) {
        int d = dst[e];
        int pos = row_start[d] + atomicAdd(&cursor[d], 1);
        csr_src[pos] = src[e];
    }
}

__global__ void pad_kernel(const int* __restrict__ deg, const int* __restrict__ row_start,
                           int* __restrict__ csr_src) {
    int n = blockIdx.x * blockDim.x + threadIdx.x;
    if (n < N_NODES) {
        int d = deg[n], pd = (d + 3) & ~3, rs = row_start[n];
        for (int p = d; p < pd; p++) csr_src[rs + p] = N_NODES;  // dummy zero row
    }
}

__global__ void zero_dummy_kernel(short* __restrict__ ha, short* __restrict__ hb) {
    int t = threadIdx.x;
    if (t < HID) {
        ha[(size_t)N_NODES * HID + t] = 0;
        hb[(size_t)N_NODES * HID + t] = 0;
    }
}

// ---------------- weight converts: col-major bf16 for MFMA B operands ----------------
__global__ void convert_win_kernel(const float* __restrict__ W, short* __restrict__ Wt) {
    int n = blockIdx.x;    // 0..95
    int k = threadIdx.x;   // 0..511
    Wt[(size_t)n * NFEAT + k] = (short)f2bf(W[(size_t)k * HID + n]);
}

__global__ void convert_wout_kernel(const float* __restrict__ W, short* __restrict__ Wt) {
    int n = blockIdx.x;    // 0..63
    int k = threadIdx.x;   // 0..95
    Wt[(size_t)n * HID + k] = (short)f2bf(W[(size_t)k * NCLASS + n]);
}

// ---------------- input GEMM via MFMA bf16: h = relu(x @ W_in + b_in) -> h_bf, x0 fp32 ----
__global__ __launch_bounds__(256) void gemm_in_kernel(
        const float* __restrict__ x, const short* __restrict__ Wt,
        const float* __restrict__ b, short* __restrict__ h_bf, float* __restrict__ x0) {
    __shared__ short A_lds[64 * 40];
    int tid  = threadIdx.x;
    int wave = tid >> 6, lane = tid & 63;
    int quad = lane >> 4, l16 = lane & 15;
    int row0 = blockIdx.x * 64;
    int m0   = wave * 16;

    f32x4 acc[6];
#pragma unroll
    for (int n = 0; n < 6; n++) acc[n] = (f32x4){0.f, 0.f, 0.f, 0.f};

    for (int k0 = 0; k0 < NFEAT; k0 += 32) {
#pragma unroll
        for (int it = 0; it < 2; it++) {
            int s = tid + it * 256;
            int r = s >> 3, kq = s & 7;
            int gr = row0 + r; if (gr >= N_NODES) gr = N_NODES - 1;
            float4 v = *(const float4*)&x[(size_t)gr * NFEAT + k0 + kq * 4];
            uint2 pk;
            pk.x = (unsigned)f2bf(v.x) | ((unsigned)f2bf(v.y) << 16);
            pk.y = (unsigned)f2bf(v.z) | ((unsigned)f2bf(v.w) << 16);
            *(uint2*)&A_lds[r * 40 + kq * 4] = pk;
        }
        __syncthreads();
        short8 afrag = *(const short8*)&A_lds[(m0 + l16) * 40 + quad * 8];
#pragma unroll
        for (int n = 0; n < 6; n++) {
            short8 bfrag = *(const short8*)&Wt[(size_t)(n * 16 + l16) * NFEAT + k0 + quad * 8];
            acc[n] = __builtin_amdgcn_mfma_f32_16x16x32_bf16(afrag, bfrag, acc[n], 0, 0, 0);
        }
        __syncthreads();
    }
#pragma unroll
    for (int n = 0; n < 6; n++) {
        int col = n * 16 + l16;
        float bias = b[col];
#pragma unroll
        for (int r = 0; r < 4; r++) {
            int grow = row0 + m0 + quad * 4 + r;
            if (grow < N_NODES) {
                float v = acc[n][r] + bias;
                v = v > 0.f ? v : 0.f;
                h_bf[(size_t)grow * HID + col] = (short)f2bf(v);
                x0[(size_t)grow * HID + col]   = v;
            }
        }
    }
}

// ---------------- fused layer: bf16 gather + residual mix + fp32 96x96 GEMM + relu -> bf16 --
// block (12,32): ty = node (32/block), tx = 8-feature chunk (12 = 96/8). 16B gathers.
__global__ __launch_bounds__(384) void layer_kernel(
        const short* __restrict__ h_in, const float* __restrict__ x0,
        const int* __restrict__ row_start, const int* __restrict__ deg,
        const int* __restrict__ csr_src, const float* __restrict__ W,
        float beta, short* __restrict__ h_out) {
    __shared__ float Ws[96][100];   // fp32 weights, padded
    __shared__ float As[32][100];   // hc fp32, padded
    int tx = threadIdx.x;           // 0..11
    int ty = threadIdx.y;           // 0..31
    int tid = ty * 12 + tx;
    int node = blockIdx.x * 32 + ty;
    int nclamp = node < N_NODES ? node : N_NODES - 1;

    // stage W (fp32) into LDS; in flight during gather
#pragma unroll
    for (int j = 0; j < 6; j++) {
        int s = tid + j * 384;                  // float4 index, 2304 total
        int r = s / 24, cq = s % 24;
        *(float4*)&Ws[r][cq * 4] = ((const float4*)W)[s];
    }

    int s = row_start[nclamp];
    int d = deg[nclamp];
    int nq = (d + 3) >> 2;
    const int4* c4 = (const int4*)(csr_src + s);
    float acc[8];
#pragma unroll
    for (int j = 0; j < 8; j++) acc[j] = 0.f;
    for (int i = 0; i < nq; i++) {
        int4 idx = c4[i];
        uint4 a0 = *(const uint4*)&h_in[(size_t)idx.x * HID + tx * 8];
        uint4 a1 = *(const uint4*)&h_in[(size_t)idx.y * HID + tx * 8];
        uint4 a2 = *(const uint4*)&h_in[(size_t)idx.z * HID + tx * 8];
        uint4 a3 = *(const uint4*)&h_in[(size_t)idx.w * HID + tx * 8];
        acc[0] += bflo(a0.x) + bflo(a1.x) + bflo(a2.x) + bflo(a3.x);
        acc[1] += bfhi(a0.x) + bfhi(a1.x) + bfhi(a2.x) + bfhi(a3.x);
        acc[2] += bflo(a0.y) + bflo(a1.y) + bflo(a2.y) + bflo(a3.y);
        acc[3] += bfhi(a0.y) + bfhi(a1.y) + bfhi(a2.y) + bfhi(a3.y);
        acc[4] += bflo(a0.z) + bflo(a1.z) + bflo(a2.z) + bflo(a3.z);
        acc[5] += bfhi(a0.z) + bfhi(a1.z) + bfhi(a2.z) + bfhi(a3.z);
        acc[6] += bflo(a0.w) + bflo(a1.w) + bflo(a2.w) + bflo(a3.w);
        acc[7] += bfhi(a0.w) + bfhi(a1.w) + bfhi(a2.w) + bfhi(a3.w);
    }
    float4 r0 = *(const float4*)&x0[(size_t)nclamp * HID + tx * 8];
    float4 r1 = *(const float4*)&x0[(size_t)nclamp * HID + tx * 8 + 4];
    float hc[8];
    hc[0] = (1.f - ALPHA) * acc[0] + ALPHA * r0.x;
    hc[1] = (1.f - ALPHA) * acc[1] + ALPHA * r0.y;
    hc[2] = (1.f - ALPHA) * acc[2] + ALPHA * r0.z;
    hc[3] = (1.f - ALPHA) * acc[3] + ALPHA * r0.w;
    hc[4] = (1.f - ALPHA) * acc[4] + ALPHA * r1.x;
    hc[5] = (1.f - ALPHA) * acc[5] + ALPHA * r1.y;
    hc[6] = (1.f - ALPHA) * acc[6] + ALPHA * r1.z;
    hc[7] = (1.f - ALPHA) * acc[7] + ALPHA * r1.w;
    *(float4*)&As[ty][tx * 8]     = *(float4*)&hc[0];
    *(float4*)&As[ty][tx * 8 + 4] = *(float4*)&hc[4];
    __syncthreads();

    // GEMM: cols c0..c0+7 per thread, fp32
    int c0 = tx * 8;
    float g[8];
#pragma unroll
    for (int j = 0; j < 8; j++) g[j] = 0.f;
#pragma unroll 4
    for (int k = 0; k < 96; k++) {
        float a = As[ty][k];
        float4 w0 = *(const float4*)&Ws[k][c0];
        float4 w1 = *(const float4*)&Ws[k][c0 + 4];
        g[0] += a * w0.x; g[1] += a * w0.y; g[2] += a * w0.z; g[3] += a * w0.w;
        g[4] += a * w1.x; g[5] += a * w1.y; g[6] += a * w1.z; g[7] += a * w1.w;
    }
    if (node < N_NODES) {
        float ob = 1.0f - beta;
        unsigned int pk[4];
#pragma unroll
        for (int j = 0; j < 4; j++) {
            float v0 = ob * hc[2*j]   + beta * g[2*j];
            float v1 = ob * hc[2*j+1] + beta * g[2*j+1];
            v0 = v0 > 0.f ? v0 : 0.f;
            v1 = v1 > 0.f ? v1 : 0.f;
            pk[j] = (unsigned)f2bf(v0) | ((unsigned)f2bf(v1) << 16);
        }
        *(uint4*)&h_out[(size_t)node * HID + c0] = *(uint4*)pk;
    }
}

// ---------------- output GEMM (MFMA bf16) + fused log_softmax ----------------
// 64 rows/block, 4 waves x 16 rows; 4 n-tiles (64 cols), K=96 = 3 MFMA steps.
__global__ __launch_bounds__(256) void out_kernel(
        const short* __restrict__ h_bf, const short* __restrict__ Wt,
        const float* __restrict__ b, float* __restrict__ out) {
    int tid = threadIdx.x;
    int wave = tid >> 6, lane = tid & 63;
    int quad = lane >> 4, l16 = lane & 15;
    int row0 = blockIdx.x * 64 + wave * 16;

    f32x4 acc[4];
#pragma unroll
    for (int n = 0; n < 4; n++) acc[n] = (f32x4){0.f, 0.f, 0.f, 0.f};

    int arow = row0 + l16; if (arow > N_NODES) arow = N_NODES;  // dummy row is zero
#pragma unroll
    for (int ks = 0; ks < 3; ks++) {
        short8 afrag = *(const short8*)&h_bf[(size_t)arow * HID + ks * 32 + quad * 8];
#pragma unroll
        for (int n = 0; n < 4; n++) {
            short8 bfrag = *(const short8*)&Wt[(size_t)(n * 16 + l16) * HID + ks * 32 + quad * 8];
            acc[n] = __builtin_amdgcn_mfma_f32_16x16x32_bf16(afrag, bfrag, acc[n], 0, 0, 0);
        }
    }
#pragma unroll
    for (int n = 0; n < 4; n++) {
        float bias = b[n * 16 + l16];
#pragma unroll
        for (int r = 0; r < 4; r++) acc[n][r] += bias;
    }
    // per-row (quad,r) log_softmax over 64 cols spread across 16 lanes x 4 n-tiles
#pragma unroll
    for (int r = 0; r < 4; r++) {
        float m = acc[0][r];
        m = fmaxf(m, acc[1][r]); m = fmaxf(m, acc[2][r]); m = fmaxf(m, acc[3][r]);
#pragma unroll
        for (int off = 1; off < 16; off <<= 1) m = fmaxf(m, __shfl_xor(m, off));
        float s = __expf(acc[0][r] - m) + __expf(acc[1][r] - m)
                + __expf(acc[2][r] - m) + __expf(acc[3][r] - m);
#pragma unroll
        for (int off = 1; off < 16; off <<= 1) s += __shfl_xor(s, off);
        float lse = m + __logf(s);
        int grow = row0 + quad * 4 + r;
        if (grow < N_NODES) {
#pragma unroll
            for (int n = 0; n < 4; n++)
                out[(size_t)grow * NCLASS + n * 16 + l16] = acc[n][r] - lse;
        }
    }
}

extern "C" void kernel_launch(void* const* d_in, const int* in_sizes, int n_in,
                              void* d_out, int out_size, void* d_ws, size_t ws_size,
                              hipStream_t stream) {
    const float* x      = (const float*)d_in[0];
    const int*   ei     = (const int*)d_in[1];
    const int*   srcp   = ei;
    const int*   dstp   = ei + N_EDGES;
    const float* W_in   = (const float*)d_in[2];
    const float* b_in   = (const float*)d_in[3];
    const float* conv_W = (const float*)d_in[4];
    const float* W_out  = (const float*)d_in[5];
    const float* b_out  = (const float*)d_in[6];
    float* out = (float*)d_out;

    short* h_a = (short*)d_ws;                               // (N+1) x HID bf16
    short* h_b = h_a + (size_t)(N_NODES + 1) * HID;
    float* x0  = (float*)(h_b + (size_t)(N_NODES + 1) * HID);
    short* Wt_in  = (short*)(x0 + (size_t)N_NODES * HID);    // 96 x 512
    short* Wt_out = Wt_in + (size_t)HID * NFEAT;             // 64 x 96
    int* deg       = (int*)(Wt_out + (size_t)NCLASS * HID);
    int* row_start = deg + N_NODES;
    int* cursor    = row_start + N_NODES;
    int* blk_sum   = cursor + N_NODES;
    int* blk_off   = blk_sum + 64;
    int* csr_src   = blk_off + 64;                           // <= N_EDGES + 3*N_NODES ints

    hipMemsetAsync(deg,    0, N_NODES * sizeof(int), stream);
    hipMemsetAsync(cursor, 0, N_NODES * sizeof(int), stream);
    hist_kernel<<<(N_EDGES + 255) / 256, 256, 0, stream>>>(dstp, deg);
    scan1_kernel<<<NSB, 1024, 0, stream>>>(deg, row_start, blk_sum);
    scan2_kernel<<<1, 64, 0, stream>>>(blk_sum, blk_off);
    scan3_kernel<<<NSB, 1024, 0, stream>>>(row_start, blk_off);
    fill_kernel<<<(N_EDGES + 255) / 256, 256, 0, stream>>>(srcp, dstp, row_start, cursor, csr_src);
    pad_kernel<<<(N_NODES + 255) / 256, 256, 0, stream>>>(deg, row_start, csr_src);

    convert_win_kernel<<<HID, NFEAT, 0, stream>>>(W_in, Wt_in);
    convert_wout_kernel<<<NCLASS, HID, 0, stream>>>(W_out, Wt_out);
    gemm_in_kernel<<<(N_NODES + 63) / 64, 256, 0, stream>>>(x, Wt_in, b_in, h_a, x0);
    zero_dummy_kernel<<<1, 128, 0, stream>>>(h_a, h_b);

    short* cur = h_a;
    short* nxt = h_b;
    for (int l = 0; l < NUM_LAYERS; l++) {
        float beta = logf(0.5f / (float)(l + 1) + 1.0f);
        layer_kernel<<<(N_NODES + 31) / 32, dim3(12, 32), 0, stream>>>(
            cur, x0, row_start, deg, csr_src, conv_W + (size_t)l * HID * HID, beta, nxt);
        short* t = cur; cur = nxt; nxt = t;
    }

    out_kernel<<<(N_NODES + 63) / 64, 256, 0, stream>>>(cur, Wt_out, b_out, out);
}